// Round 6
// baseline (306.171 us; speedup 1.0000x reference)
//
#include <hip/hip_runtime.h>
#include <hip/hip_fp16.h>

typedef __attribute__((ext_vector_type(8))) _Float16 f16x8;
typedef __attribute__((ext_vector_type(4))) float f32x4;

#define M_DIM 8192
#define N_DIM 4096
#define K_DIM 4096
#define BM 256
#define BN 256
#define BK 64
#define NT (K_DIM / BK)      // 64 K-tiles
#define ITERS (NT / 2)       // 32 iterations, 2 tiles each

__constant__ float FP4_LUT[16] = {0.f, 0.5f, 1.f, 1.5f, 2.f, 3.f, 4.f, 6.f,
                                  -0.f, -0.5f, -1.f, -1.5f, -2.f, -3.f, -4.f, -6.f};

__device__ inline void glds16(const void* g, void* l) {
    __builtin_amdgcn_global_load_lds(
        (const __attribute__((address_space(1))) void*)g,
        (__attribute__((address_space(3))) void*)l, 16, 0, 0);
}

// ---- prepass 1: x fp32 -> fp16 ----
__global__ __launch_bounds__(256) void cvt_x_kernel(const float* __restrict__ x,
                                                    _Float16* __restrict__ xh) {
    int i = (blockIdx.x * 256 + threadIdx.x) * 8;
    const float4* p = (const float4*)(x + i);
    float4 a = p[0], b = p[1];
    f16x8 h;
    h[0] = (_Float16)a.x; h[1] = (_Float16)a.y;
    h[2] = (_Float16)a.z; h[3] = (_Float16)a.w;
    h[4] = (_Float16)b.x; h[5] = (_Float16)b.y;
    h[6] = (_Float16)b.z; h[7] = (_Float16)b.w;
    *(f16x8*)(xh + i) = h;
}

// ---- prepass 2: packed fp4 bytes -> fp16 W[N][K] row-major ----
__global__ __launch_bounds__(256) void dequant_w_kernel(const int* __restrict__ w,
                                                        const float* __restrict__ wsc,
                                                        _Float16* __restrict__ wh) {
    int t = blockIdx.x * 256 + threadIdx.x;
    int4 b4 = ((const int4*)w)[t];
    int o  = t >> 9;
    int j0 = (t & 511) << 2;
    float s = wsc[(o << 8) + (j0 >> 3)];
    f16x8 h;
    int b;
    b = b4.x; h[0] = (_Float16)(FP4_LUT[(b >> 4) & 15] * s); h[1] = (_Float16)(FP4_LUT[b & 15] * s);
    b = b4.y; h[2] = (_Float16)(FP4_LUT[(b >> 4) & 15] * s); h[3] = (_Float16)(FP4_LUT[b & 15] * s);
    b = b4.z; h[4] = (_Float16)(FP4_LUT[(b >> 4) & 15] * s); h[5] = (_Float16)(FP4_LUT[b & 15] * s);
    b = b4.w; h[6] = (_Float16)(FP4_LUT[(b >> 4) & 15] * s); h[7] = (_Float16)(FP4_LUT[b & 15] * s);
    *(f16x8*)(wh + ((long)o << 12) + (j0 << 1)) = h;
}

// ===================== 8-phase 256x256 GEMM (m201-style port) =====================
// LDS per dbuf (f16 offsets): A.kh0 @0, A.kh1 @8192, B.kh0 @16384, B.kh1 @24576.
// T2 XOR swizzle: LDS 16B-slot s at row r holds logical col-slot s ^ ((r>>1)&3).
// Write side: linear glds dest + pre-swizzled global source (rule #21).
// Read side: slot = kg ^ ((fr>>1)&3) -> residual 2-way aliasing only (free, m136).
// NOTE (r6): no sched_barrier(0) — ds_reads are C++ loads, so the compiler
// emits fine-grained lgkmcnt before each dependent MFMA; pinning the schedule
// with sched_barrier forced a full-drain-then-burst serialization (r5 = 50%).

#define VM8 asm volatile("s_waitcnt vmcnt(8)" ::: "memory")
#define VM4 asm volatile("s_waitcnt vmcnt(4)" ::: "memory")
#define VM0 asm volatile("s_waitcnt vmcnt(0)" ::: "memory")
#define VMX ((void)0)

#define STAGE(OP, SD, KH, KOFF) do {                                           \
    _Float16* _d = lds + (SD)*32768 + (OP)*16384 + (KH)*8192 + (wid << 9);     \
    const _Float16* _s = ((OP) ? srcB : srcA) + (KOFF);                        \
    glds16(_s, _d);                                                            \
    glds16(_s + (size_t)128 * K_DIM, _d + 4096);                               \
  } while (0)

#define PHASE(CB, KH, MH, DOB, VMS, ...) do {                                  \
    const _Float16* _cb = lds + (CB)*32768 + (KH)*8192;                        \
    if (DOB) {                                                                 \
      bf[0] = *(const f16x8*)(_cb + b_off);                                    \
      bf[1] = *(const f16x8*)(_cb + b_off + 512);                              \
      bf[2] = *(const f16x8*)(_cb + b_off + 1024);                             \
      bf[3] = *(const f16x8*)(_cb + b_off + 1536);                             \
    }                                                                          \
    af[0] = *(const f16x8*)(_cb + a_off + (MH)*2048);                          \
    af[1] = *(const f16x8*)(_cb + a_off + (MH)*2048 + 512);                    \
    af[2] = *(const f16x8*)(_cb + a_off + (MH)*2048 + 1024);                   \
    af[3] = *(const f16x8*)(_cb + a_off + (MH)*2048 + 1536);                   \
    __VA_ARGS__;                                                               \
    __builtin_amdgcn_s_barrier();                                              \
    asm volatile("s_waitcnt lgkmcnt(0)" ::: "memory");                         \
    __builtin_amdgcn_s_setprio(1);                                             \
    _Pragma("unroll")                                                          \
    for (int mf = 0; mf < 4; ++mf) {                                           \
      _Pragma("unroll")                                                        \
      for (int nf = 0; nf < 4; ++nf)                                           \
        acc[(MH)*4 + mf][nf] = __builtin_amdgcn_mfma_f32_16x16x32_f16(         \
            af[mf], bf[nf], acc[(MH)*4 + mf][nf], 0, 0, 0);                    \
    }                                                                          \
    __builtin_amdgcn_s_setprio(0);                                             \
    VMS;                                                                       \
    __builtin_amdgcn_s_barrier();                                              \
  } while (0)

__global__ __launch_bounds__(512, 2) void gemm_f16_8ph(const _Float16* __restrict__ A,
                                                       const _Float16* __restrict__ B,
                                                       const float* __restrict__ bias,
                                                       float* __restrict__ C) {
    __shared__ _Float16 lds[2 * 32768];   // 128 KiB

    const int tid  = threadIdx.x;
    const int wid  = tid >> 6;
    const int lane = tid & 63;
    const int fr   = lane & 15;
    const int kg   = lane >> 4;
    const int wm   = wid >> 2;     // 0..1
    const int wn   = wid & 3;      // 0..3

    // T1: XCD-aware swizzle (512 blocks, 64/XCD, consecutive share B-panel)
    int bid = blockIdx.x;
    int nb  = (bid & 7) * 64 + (bid >> 3);
    const int brow = (nb & 31) * BM;
    const int bcol = (nb >> 5) * BN;

    // staging source: thread covers row tid>>2; PRE-SWIZZLED col slot
    // (write row = tid>>2, so (row>>1)&3 = (tid>>3)&3; +128 rows preserves it)
    const int s_col = (((tid & 3) ^ ((tid >> 3) & 3)) << 3);
    const _Float16* srcA = A + (size_t)(brow + (tid >> 2)) * K_DIM + s_col;
    const _Float16* srcB = B + (size_t)(bcol + (tid >> 2)) * K_DIM + s_col;

    // ds_read offsets (f16): row*32 + swizzled 16B slot; row%16 == fr,
    // (row>>1)&3 = (fr>>1)&3 independent of m/n (16-row steps are 0 mod 8).
    const int swz   = ((kg ^ ((fr >> 1) & 3)) << 3);
    const int a_off = (wm * 128 + fr) * 32 + swz;
    const int b_off = 16384 + (wn * 64 + fr) * 32 + swz;

    f16x8 af[4], bf[4];
    f32x4 acc[8][4] = {};

    // prologue: t0 (all 4 halves) + t1.kh0 halves = 12 glds; retire t0.kh0
    STAGE(0, 0, 0, 0);
    STAGE(1, 0, 0, 0);
    STAGE(0, 0, 1, 32);
    STAGE(1, 0, 1, 32);
    STAGE(0, 1, 0, 64);
    STAGE(1, 1, 0, 64);
    VM8;
    __builtin_amdgcn_s_barrier();

    for (int i = 0; i < ITERS - 1; ++i) {
        const int kb = i << 7;   // = t*64, t = 2i
        PHASE(0, 0, 0, true,  VMX, STAGE(0, 1, 1, kb + 96));    // p0: stage t+1.A.kh1
        PHASE(0, 0, 1, false, VM8, STAGE(1, 1, 1, kb + 96));    // p1: t+1.B.kh1
        PHASE(0, 1, 0, true,  VMX, STAGE(0, 0, 0, kb + 128));   // p2: t+2.A.kh0
        PHASE(0, 1, 1, false, VM8, STAGE(1, 0, 0, kb + 128));   // p3: t+2.B.kh0
        PHASE(1, 0, 0, true,  VMX, STAGE(0, 0, 1, kb + 160));   // p4: t+2.A.kh1
        PHASE(1, 0, 1, false, VM8, STAGE(1, 0, 1, kb + 160));   // p5: t+2.B.kh1
        PHASE(1, 1, 0, true,  VMX, STAGE(0, 1, 0, kb + 192));   // p6: t+3.A.kh0
        PHASE(1, 1, 1, false, VM8, STAGE(1, 1, 0, kb + 192));   // p7: t+3.B.kh0
    }
    {   // drain iteration (t = NT-2): only t+1.kh1 staging remains
        const int kb = (ITERS - 1) << 7;
        PHASE(0, 0, 0, true,  VMX, STAGE(0, 1, 1, kb + 96));
        PHASE(0, 0, 1, false, VM8, STAGE(1, 1, 1, kb + 96));
        PHASE(0, 1, 0, true,  VMX, VMX);
        PHASE(0, 1, 1, false, VM4, VMX);
        PHASE(1, 0, 0, true,  VMX, VMX);
        PHASE(1, 0, 1, false, VM0, VMX);
        PHASE(1, 1, 0, true,  VMX, VMX);
        PHASE(1, 1, 1, false, VMX, VMX);
    }

    // epilogue: C/D layout col = lane&15, row = (lane>>4)*4 + reg
#pragma unroll
    for (int m = 0; m < 8; ++m) {
        int row = brow + wm * 128 + m * 16 + kg * 4;
#pragma unroll
        for (int n = 0; n < 4; ++n) {
            int col = bcol + wn * 64 + n * 16 + fr;
            float bv = bias[col];
#pragma unroll
            for (int j = 0; j < 4; ++j)
                C[(size_t)(row + j) * N_DIM + col] = acc[m][n][j] + bv;
        }
    }
}

// ---- fallback (only if ws too small) ----
__global__ __launch_bounds__(256) void fallback_kernel(const float* __restrict__ x,
                                                       const int* __restrict__ w,
                                                       const float* __restrict__ wsc,
                                                       const float* __restrict__ bias,
                                                       float* __restrict__ out) {
    long idx = (long)blockIdx.x * 256 + threadIdx.x;
    int t = (int)(idx >> 12);
    int o = (int)(idx & 4095);
    float acc = 0.f;
    for (int j = 0; j < K_DIM / 2; ++j) {
        int b = w[o * (K_DIM / 2) + j];
        float s = wsc[(o << 8) + (j >> 3)];
        acc += x[(long)t * K_DIM + 2 * j]     * (FP4_LUT[(b >> 4) & 15] * s);
        acc += x[(long)t * K_DIM + 2 * j + 1] * (FP4_LUT[b & 15] * s);
    }
    out[idx] = acc + bias[o];
}

extern "C" void kernel_launch(void* const* d_in, const int* in_sizes, int n_in,
                              void* d_out, int out_size, void* d_ws, size_t ws_size,
                              hipStream_t stream) {
    const float* x    = (const float*)d_in[0];
    const int*   w    = (const int*)d_in[1];
    const float* wsc  = (const float*)d_in[2];
    const float* bias = (const float*)d_in[3];
    float* out = (float*)d_out;

    const size_t xh_bytes = (size_t)M_DIM * K_DIM * 2;   // 64 MB
    const size_t wh_bytes = (size_t)N_DIM * K_DIM * 2;   // 32 MB

    if (ws_size >= xh_bytes + wh_bytes) {
        _Float16* xh = (_Float16*)d_ws;
        _Float16* wh = (_Float16*)((char*)d_ws + xh_bytes);
        cvt_x_kernel<<<(M_DIM * K_DIM) / (256 * 8), 256, 0, stream>>>(x, xh);
        dequant_w_kernel<<<(N_DIM * (K_DIM / 2)) / (256 * 4), 256, 0, stream>>>(w, wsc, wh);
        gemm_f16_8ph<<<(M_DIM / BM) * (N_DIM / BN), 512, 0, stream>>>(xh, wh, bias, out);
    } else {
        fallback_kernel<<<((long)M_DIM * N_DIM) / 256, 256, 0, stream>>>(x, w, wsc, bias, out);
    }
}

// Round 7
// 298.809 us; speedup vs baseline: 1.0246x; 1.0246x over previous
//
#include <hip/hip_runtime.h>
#include <hip/hip_fp16.h>

typedef __attribute__((ext_vector_type(8))) _Float16 f16x8;
typedef __attribute__((ext_vector_type(4))) float f32x4;

#define M_DIM 8192
#define N_DIM 4096
#define K_DIM 4096
#define BM 256
#define BN 256
#define BK 64
#define NT (K_DIM / BK)      // 64 K-tiles
#define ITERS (NT / 2)       // 32 iterations, 2 tiles each

__constant__ float FP4_LUT[16] = {0.f, 0.5f, 1.f, 1.5f, 2.f, 3.f, 4.f, 6.f,
                                  -0.f, -0.5f, -1.f, -1.5f, -2.f, -3.f, -4.f, -6.f};

__device__ inline void glds16(const void* g, void* l) {
    __builtin_amdgcn_global_load_lds(
        (const __attribute__((address_space(1))) void*)g,
        (__attribute__((address_space(3))) void*)l, 16, 0, 0);
}

// ---- prepass 1: x fp32 -> fp16 ----
__global__ __launch_bounds__(256) void cvt_x_kernel(const float* __restrict__ x,
                                                    _Float16* __restrict__ xh) {
    int i = (blockIdx.x * 256 + threadIdx.x) * 8;
    const float4* p = (const float4*)(x + i);
    float4 a = p[0], b = p[1];
    f16x8 h;
    h[0] = (_Float16)a.x; h[1] = (_Float16)a.y;
    h[2] = (_Float16)a.z; h[3] = (_Float16)a.w;
    h[4] = (_Float16)b.x; h[5] = (_Float16)b.y;
    h[6] = (_Float16)b.z; h[7] = (_Float16)b.w;
    *(f16x8*)(xh + i) = h;
}

// ---- prepass 2: packed fp4 bytes -> fp16 W[N][K] row-major ----
__global__ __launch_bounds__(256) void dequant_w_kernel(const int* __restrict__ w,
                                                        const float* __restrict__ wsc,
                                                        _Float16* __restrict__ wh) {
    int t = blockIdx.x * 256 + threadIdx.x;
    int4 b4 = ((const int4*)w)[t];
    int o  = t >> 9;
    int j0 = (t & 511) << 2;
    float s = wsc[(o << 8) + (j0 >> 3)];
    f16x8 h;
    int b;
    b = b4.x; h[0] = (_Float16)(FP4_LUT[(b >> 4) & 15] * s); h[1] = (_Float16)(FP4_LUT[b & 15] * s);
    b = b4.y; h[2] = (_Float16)(FP4_LUT[(b >> 4) & 15] * s); h[3] = (_Float16)(FP4_LUT[b & 15] * s);
    b = b4.z; h[4] = (_Float16)(FP4_LUT[(b >> 4) & 15] * s); h[5] = (_Float16)(FP4_LUT[b & 15] * s);
    b = b4.w; h[6] = (_Float16)(FP4_LUT[(b >> 4) & 15] * s); h[7] = (_Float16)(FP4_LUT[b & 15] * s);
    *(f16x8*)(wh + ((long)o << 12) + (j0 << 1)) = h;
}

// ===================== 8-phase 256x256 GEMM (m201-style port) =====================
// LDS per dbuf (f16 offsets): A.kh0 @0, A.kh1 @8192, B.kh0 @16384, B.kh1 @24576.
// T2 XOR swizzle: LDS 16B-slot s at row r holds logical col-slot s ^ ((r>>1)&3).
// Write side: linear glds dest + pre-swizzled global source (rule #21).
// Read side: slot = kg ^ ((fr>>1)&3) -> residual 2-way aliasing only (free, m136).
// r7: square XCD chunks (8bm x 8bn) + nontemporal C stores to cut HBM re-fetch.

#define VM8 asm volatile("s_waitcnt vmcnt(8)" ::: "memory")
#define VM4 asm volatile("s_waitcnt vmcnt(4)" ::: "memory")
#define VM0 asm volatile("s_waitcnt vmcnt(0)" ::: "memory")
#define VMX ((void)0)

#define STAGE(OP, SD, KH, KOFF) do {                                           \
    _Float16* _d = lds + (SD)*32768 + (OP)*16384 + (KH)*8192 + (wid << 9);     \
    const _Float16* _s = ((OP) ? srcB : srcA) + (KOFF);                        \
    glds16(_s, _d);                                                            \
    glds16(_s + (size_t)128 * K_DIM, _d + 4096);                               \
  } while (0)

#define PHASE(CB, KH, MH, DOB, VMS, ...) do {                                  \
    const _Float16* _cb = lds + (CB)*32768 + (KH)*8192;                        \
    if (DOB) {                                                                 \
      bf[0] = *(const f16x8*)(_cb + b_off);                                    \
      bf[1] = *(const f16x8*)(_cb + b_off + 512);                              \
      bf[2] = *(const f16x8*)(_cb + b_off + 1024);                             \
      bf[3] = *(const f16x8*)(_cb + b_off + 1536);                             \
    }                                                                          \
    af[0] = *(const f16x8*)(_cb + a_off + (MH)*2048);                          \
    af[1] = *(const f16x8*)(_cb + a_off + (MH)*2048 + 512);                    \
    af[2] = *(const f16x8*)(_cb + a_off + (MH)*2048 + 1024);                   \
    af[3] = *(const f16x8*)(_cb + a_off + (MH)*2048 + 1536);                   \
    __VA_ARGS__;                                                               \
    __builtin_amdgcn_s_barrier();                                              \
    asm volatile("s_waitcnt lgkmcnt(0)" ::: "memory");                         \
    __builtin_amdgcn_s_setprio(1);                                             \
    _Pragma("unroll")                                                          \
    for (int mf = 0; mf < 4; ++mf) {                                           \
      _Pragma("unroll")                                                        \
      for (int nf = 0; nf < 4; ++nf)                                           \
        acc[(MH)*4 + mf][nf] = __builtin_amdgcn_mfma_f32_16x16x32_f16(         \
            af[mf], bf[nf], acc[(MH)*4 + mf][nf], 0, 0, 0);                    \
    }                                                                          \
    __builtin_amdgcn_s_setprio(0);                                             \
    VMS;                                                                       \
    __builtin_amdgcn_s_barrier();                                              \
  } while (0)

__global__ __launch_bounds__(512, 2) void gemm_f16_8ph(const _Float16* __restrict__ A,
                                                       const _Float16* __restrict__ B,
                                                       const float* __restrict__ bias,
                                                       float* __restrict__ C) {
    __shared__ _Float16 lds[2 * 32768];   // 128 KiB

    const int tid  = threadIdx.x;
    const int wid  = tid >> 6;
    const int lane = tid & 63;
    const int fr   = lane & 15;
    const int kg   = lane >> 4;
    const int wm   = wid >> 2;     // 0..1
    const int wn   = wid & 3;      // 0..3

    // r7 T1: square XCD chunks. 512 blocks, chunk = bid&7 -> one XCD's L2.
    // Chunk covers 8 bm x 8 bn (A 16MB + B 16MB); bm fast -> B-panel 8x L2 reuse.
    const int c = blockIdx.x & 7;
    const int q = blockIdx.x >> 3;           // 0..63
    const int bm = (c >> 1) * 8 + (q & 7);   // 0..31
    const int bn = (c & 1) * 8 + (q >> 3);   // 0..15
    const int brow = bm * BM;
    const int bcol = bn * BN;

    // staging source: thread covers row tid>>2; PRE-SWIZZLED col slot
    // (write row = tid>>2, so (row>>1)&3 = (tid>>3)&3; +128 rows preserves it)
    const int s_col = (((tid & 3) ^ ((tid >> 3) & 3)) << 3);
    const _Float16* srcA = A + (size_t)(brow + (tid >> 2)) * K_DIM + s_col;
    const _Float16* srcB = B + (size_t)(bcol + (tid >> 2)) * K_DIM + s_col;

    // ds_read offsets (f16): row*32 + swizzled 16B slot; row%16 == fr,
    // (row>>1)&3 = (fr>>1)&3 independent of m/n (16-row steps are 0 mod 8).
    const int swz   = ((kg ^ ((fr >> 1) & 3)) << 3);
    const int a_off = (wm * 128 + fr) * 32 + swz;
    const int b_off = 16384 + (wn * 64 + fr) * 32 + swz;

    f16x8 af[4], bf[4];
    f32x4 acc[8][4] = {};

    // prologue: t0 (all 4 halves) + t1.kh0 halves = 12 glds; retire t0.kh0
    STAGE(0, 0, 0, 0);
    STAGE(1, 0, 0, 0);
    STAGE(0, 0, 1, 32);
    STAGE(1, 0, 1, 32);
    STAGE(0, 1, 0, 64);
    STAGE(1, 1, 0, 64);
    VM8;
    __builtin_amdgcn_s_barrier();

    for (int i = 0; i < ITERS - 1; ++i) {
        const int kb = i << 7;   // = t*64, t = 2i
        PHASE(0, 0, 0, true,  VMX, STAGE(0, 1, 1, kb + 96));    // p0: stage t+1.A.kh1
        PHASE(0, 0, 1, false, VM8, STAGE(1, 1, 1, kb + 96));    // p1: t+1.B.kh1
        PHASE(0, 1, 0, true,  VMX, STAGE(0, 0, 0, kb + 128));   // p2: t+2.A.kh0
        PHASE(0, 1, 1, false, VM8, STAGE(1, 0, 0, kb + 128));   // p3: t+2.B.kh0
        PHASE(1, 0, 0, true,  VMX, STAGE(0, 0, 1, kb + 160));   // p4: t+2.A.kh1
        PHASE(1, 0, 1, false, VM8, STAGE(1, 0, 1, kb + 160));   // p5: t+2.B.kh1
        PHASE(1, 1, 0, true,  VMX, STAGE(0, 1, 0, kb + 192));   // p6: t+3.A.kh0
        PHASE(1, 1, 1, false, VM8, STAGE(1, 1, 0, kb + 192));   // p7: t+3.B.kh0
    }
    {   // drain iteration (t = NT-2): only t+1.kh1 staging remains
        const int kb = (ITERS - 1) << 7;
        PHASE(0, 0, 0, true,  VMX, STAGE(0, 1, 1, kb + 96));
        PHASE(0, 0, 1, false, VM8, STAGE(1, 1, 1, kb + 96));
        PHASE(0, 1, 0, true,  VMX, VMX);
        PHASE(0, 1, 1, false, VM4, VMX);
        PHASE(1, 0, 0, true,  VMX, VMX);
        PHASE(1, 0, 1, false, VM0, VMX);
        PHASE(1, 1, 0, true,  VMX, VMX);
        PHASE(1, 1, 1, false, VMX, VMX);
    }

    // epilogue: C/D layout col = lane&15, row = (lane>>4)*4 + reg.
    // Nontemporal stores: C is write-once — keep it out of L2/L3 so A/B stay
    // resident for the other blocks (FETCH_SIZE lever).
#pragma unroll
    for (int m = 0; m < 8; ++m) {
        int row = brow + wm * 128 + m * 16 + kg * 4;
#pragma unroll
        for (int n = 0; n < 4; ++n) {
            int col = bcol + wn * 64 + n * 16 + fr;
            float bv = bias[col];
#pragma unroll
            for (int j = 0; j < 4; ++j)
                __builtin_nontemporal_store(acc[m][n][j] + bv,
                                            &C[(size_t)(row + j) * N_DIM + col]);
        }
    }
}

// ---- fallback (only if ws too small) ----
__global__ __launch_bounds__(256) void fallback_kernel(const float* __restrict__ x,
                                                       const int* __restrict__ w,
                                                       const float* __restrict__ wsc,
                                                       const float* __restrict__ bias,
                                                       float* __restrict__ out) {
    long idx = (long)blockIdx.x * 256 + threadIdx.x;
    int t = (int)(idx >> 12);
    int o = (int)(idx & 4095);
    float acc = 0.f;
    for (int j = 0; j < K_DIM / 2; ++j) {
        int b = w[o * (K_DIM / 2) + j];
        float s = wsc[(o << 8) + (j >> 3)];
        acc += x[(long)t * K_DIM + 2 * j]     * (FP4_LUT[(b >> 4) & 15] * s);
        acc += x[(long)t * K_DIM + 2 * j + 1] * (FP4_LUT[b & 15] * s);
    }
    out[idx] = acc + bias[o];
}

extern "C" void kernel_launch(void* const* d_in, const int* in_sizes, int n_in,
                              void* d_out, int out_size, void* d_ws, size_t ws_size,
                              hipStream_t stream) {
    const float* x    = (const float*)d_in[0];
    const int*   w    = (const int*)d_in[1];
    const float* wsc  = (const float*)d_in[2];
    const float* bias = (const float*)d_in[3];
    float* out = (float*)d_out;

    const size_t xh_bytes = (size_t)M_DIM * K_DIM * 2;   // 64 MB
    const size_t wh_bytes = (size_t)N_DIM * K_DIM * 2;   // 32 MB

    if (ws_size >= xh_bytes + wh_bytes) {
        _Float16* xh = (_Float16*)d_ws;
        _Float16* wh = (_Float16*)((char*)d_ws + xh_bytes);
        cvt_x_kernel<<<(M_DIM * K_DIM) / (256 * 8), 256, 0, stream>>>(x, xh);
        dequant_w_kernel<<<(N_DIM * (K_DIM / 2)) / (256 * 4), 256, 0, stream>>>(w, wsc, wh);
        gemm_f16_8ph<<<(M_DIM / BM) * (N_DIM / BN), 512, 0, stream>>>(xh, wh, bias, out);
    } else {
        fallback_kernel<<<((long)M_DIM * N_DIM) / 256, 256, 0, stream>>>(x, w, wsc, bias, out);
    }
}

// Round 8
// 283.241 us; speedup vs baseline: 1.0810x; 1.0550x over previous
//
#include <hip/hip_runtime.h>
#include <hip/hip_fp16.h>

typedef __attribute__((ext_vector_type(8))) _Float16 f16x8;
typedef __attribute__((ext_vector_type(4))) float f32x4;

#define M_DIM 8192
#define N_DIM 4096
#define K_DIM 4096
#define BM 256
#define BN 256
#define BK 64
#define NT (K_DIM / BK)      // 64 K-tiles
#define ITERS (NT / 2)       // 32 iterations, 2 tiles each

__constant__ float FP4_LUT[16] = {0.f, 0.5f, 1.f, 1.5f, 2.f, 3.f, 4.f, 6.f,
                                  -0.f, -0.5f, -1.f, -1.5f, -2.f, -3.f, -4.f, -6.f};

__device__ inline void glds16(const void* g, void* l) {
    __builtin_amdgcn_global_load_lds(
        (const __attribute__((address_space(1))) void*)g,
        (__attribute__((address_space(3))) void*)l, 16, 0, 0);
}

// ---- prepass 1: x fp32 -> fp16 ----
__global__ __launch_bounds__(256) void cvt_x_kernel(const float* __restrict__ x,
                                                    _Float16* __restrict__ xh) {
    int i = (blockIdx.x * 256 + threadIdx.x) * 8;
    const float4* p = (const float4*)(x + i);
    float4 a = p[0], b = p[1];
    f16x8 h;
    h[0] = (_Float16)a.x; h[1] = (_Float16)a.y;
    h[2] = (_Float16)a.z; h[3] = (_Float16)a.w;
    h[4] = (_Float16)b.x; h[5] = (_Float16)b.y;
    h[6] = (_Float16)b.z; h[7] = (_Float16)b.w;
    *(f16x8*)(xh + i) = h;
}

// ---- prepass 2: packed fp4 bytes -> fp16 W[N][K] row-major ----
__global__ __launch_bounds__(256) void dequant_w_kernel(const int* __restrict__ w,
                                                        const float* __restrict__ wsc,
                                                        _Float16* __restrict__ wh) {
    int t = blockIdx.x * 256 + threadIdx.x;
    int4 b4 = ((const int4*)w)[t];
    int o  = t >> 9;
    int j0 = (t & 511) << 2;
    float s = wsc[(o << 8) + (j0 >> 3)];
    f16x8 h;
    int b;
    b = b4.x; h[0] = (_Float16)(FP4_LUT[(b >> 4) & 15] * s); h[1] = (_Float16)(FP4_LUT[b & 15] * s);
    b = b4.y; h[2] = (_Float16)(FP4_LUT[(b >> 4) & 15] * s); h[3] = (_Float16)(FP4_LUT[b & 15] * s);
    b = b4.z; h[4] = (_Float16)(FP4_LUT[(b >> 4) & 15] * s); h[5] = (_Float16)(FP4_LUT[b & 15] * s);
    b = b4.w; h[6] = (_Float16)(FP4_LUT[(b >> 4) & 15] * s); h[7] = (_Float16)(FP4_LUT[b & 15] * s);
    *(f16x8*)(wh + ((long)o << 12) + (j0 << 1)) = h;
}

// ============ 8-phase 256x256 GEMM, register-prefetch pipeline (r8) ============
// Phase p: {stage glds | prefetch frags for phase p+1 | lgkmcnt(4|8) retiring
// only phase p-1's reads | MFMA on regs loaded at p-1 | [vmcnt(6) even phases]
// | ONE barrier}. LDS pipe (prefetch) overlaps matrix pipe (MFMA).
// WAR: lgkmcnt(N) pinned before barrier => by barrier arrival, all prior-phase
// reads delivered; stage at p overwrites a region last-read at p-2. RAW:
// vmcnt(6)@even retires the k-half staged 6 phases back, one phase before its
// prefetch-read; the phase-end barrier publishes. Prologue vmcnt(2);
// drain iter vmcnt(4)@p2, vmcnt(0)@p4.
// T2 XOR swizzle unchanged (bank-conflict 0). Square XCD chunks (r7, FETCH 3.3x).

#define VM6 asm volatile("s_waitcnt vmcnt(6)" ::: "memory")
#define VM4 asm volatile("s_waitcnt vmcnt(4)" ::: "memory")
#define VM2 asm volatile("s_waitcnt vmcnt(2)" ::: "memory")
#define VM0 asm volatile("s_waitcnt vmcnt(0)" ::: "memory")
#define LG8 asm volatile("s_waitcnt lgkmcnt(8)" ::: "memory")
#define LG4 asm volatile("s_waitcnt lgkmcnt(4)" ::: "memory")
#define LG0 asm volatile("s_waitcnt lgkmcnt(0)" ::: "memory")
#define NOP ((void)0)

#define STAGE(OP, SD, KH, KOFF) do {                                           \
    _Float16* _d = lds + (SD)*32768 + (OP)*16384 + (KH)*8192 + (wid << 9);     \
    const _Float16* _s = ((OP) ? srcB : srcA) + (KOFF);                        \
    glds16(_s, _d);                                                            \
    glds16(_s + (size_t)128 * K_DIM, _d + 4096);                               \
  } while (0)

// DOAF/DOBF: issue prefetch reads for next phase's A-frags / B-frags.
// LGW: lgkm wait leaving exactly this phase's prefetch in flight.
// MHC/AFC/BFC: this phase's MFMA m-half and operand register sets.
#define PH(DOAF, NCB, NKH, NMH, AFN, DOBF, BFN, LGW, MHC, AFC, BFC, STG, VMW) do { \
    STG;                                                                       \
    const _Float16* _nb = lds + (NCB)*32768 + (NKH)*8192;                      \
    if (DOAF) {                                                                \
      AFN[0] = *(const f16x8*)(_nb + a_off + (NMH)*2048);                      \
      AFN[1] = *(const f16x8*)(_nb + a_off + (NMH)*2048 + 512);                \
      AFN[2] = *(const f16x8*)(_nb + a_off + (NMH)*2048 + 1024);               \
      AFN[3] = *(const f16x8*)(_nb + a_off + (NMH)*2048 + 1536);               \
    }                                                                          \
    if (DOBF) {                                                                \
      BFN[0] = *(const f16x8*)(_nb + b_off);                                   \
      BFN[1] = *(const f16x8*)(_nb + b_off + 512);                             \
      BFN[2] = *(const f16x8*)(_nb + b_off + 1024);                            \
      BFN[3] = *(const f16x8*)(_nb + b_off + 1536);                            \
    }                                                                          \
    LGW;                                                                       \
    __builtin_amdgcn_s_setprio(1);                                             \
    _Pragma("unroll")                                                          \
    for (int mf = 0; mf < 4; ++mf) {                                           \
      _Pragma("unroll")                                                        \
      for (int nf = 0; nf < 4; ++nf)                                           \
        acc[(MHC)*4 + mf][nf] = __builtin_amdgcn_mfma_f32_16x16x32_f16(        \
            AFC[mf], BFC[nf], acc[(MHC)*4 + mf][nf], 0, 0, 0);                 \
    }                                                                          \
    __builtin_amdgcn_s_setprio(0);                                             \
    VMW;                                                                       \
    __builtin_amdgcn_s_barrier();                                              \
  } while (0)

__global__ __launch_bounds__(512, 2) void gemm_f16_pf(const _Float16* __restrict__ A,
                                                      const _Float16* __restrict__ B,
                                                      const float* __restrict__ bias,
                                                      float* __restrict__ C) {
    __shared__ _Float16 lds[2 * 32768];   // 128 KiB

    const int tid  = threadIdx.x;
    const int wid  = tid >> 6;
    const int lane = tid & 63;
    const int fr   = lane & 15;
    const int kg   = lane >> 4;
    const int wm   = wid >> 2;     // 0..1
    const int wn   = wid & 3;      // 0..3

    // square XCD chunks: 8bm x 8bn per XCD (r7: FETCH 650->198 MB)
    const int c = blockIdx.x & 7;
    const int q = blockIdx.x >> 3;           // 0..63
    const int bm = (c >> 1) * 8 + (q & 7);   // 0..31
    const int bn = (c & 1) * 8 + (q >> 3);   // 0..15
    const int brow = bm * BM;
    const int bcol = bn * BN;

    // staging source: row tid>>2; pre-swizzled col slot (rule #21)
    const int s_col = (((tid & 3) ^ ((tid >> 3) & 3)) << 3);
    const _Float16* srcA = A + (size_t)(brow + (tid >> 2)) * K_DIM + s_col;
    const _Float16* srcB = B + (size_t)(bcol + (tid >> 2)) * K_DIM + s_col;

    // ds_read offsets: row*32 + swizzled 16B slot
    const int swz   = ((kg ^ ((fr >> 1) & 3)) << 3);
    const int a_off = (wm * 128 + fr) * 32 + swz;
    const int b_off = 16384 + (wn * 64 + fr) * 32 + swz;

    f16x8 af0[4], af1[4], bf0[4], bf1[4];
    f32x4 acc[8][4] = {};

    // prologue: stage buf0 (t0 full) then buf1.kh0 (t1); retire buf0+buf1.A.kh0
    STAGE(0, 0, 0, 0);
    STAGE(1, 0, 0, 0);
    STAGE(0, 0, 1, 32);
    STAGE(1, 0, 1, 32);
    STAGE(0, 1, 0, 64);
    STAGE(1, 1, 0, 64);
    VM2;
    __builtin_amdgcn_s_barrier();
    // prefetch phase-0 operands: buf0.kh0, m-half 0 + B
    af0[0] = *(const f16x8*)(lds + a_off);
    af0[1] = *(const f16x8*)(lds + a_off + 512);
    af0[2] = *(const f16x8*)(lds + a_off + 1024);
    af0[3] = *(const f16x8*)(lds + a_off + 1536);
    bf0[0] = *(const f16x8*)(lds + b_off);
    bf0[1] = *(const f16x8*)(lds + b_off + 512);
    bf0[2] = *(const f16x8*)(lds + b_off + 1024);
    bf0[3] = *(const f16x8*)(lds + b_off + 1536);

    for (int i = 0; i < ITERS - 1; ++i) {
        const int kb = i << 7;
        PH(1, 0,0,1, af1, 0,bf0, LG4, 0, af0, bf0, STAGE(0,1,1,kb+96),  VM6); // p0
        PH(1, 0,1,0, af0, 1,bf1, LG8, 1, af1, bf0, STAGE(1,1,1,kb+96),  NOP); // p1
        PH(1, 0,1,1, af1, 0,bf0, LG4, 0, af0, bf1, STAGE(0,0,0,kb+128), VM6); // p2
        PH(1, 1,0,0, af0, 1,bf0, LG8, 1, af1, bf1, STAGE(1,0,0,kb+128), NOP); // p3
        PH(1, 1,0,1, af1, 0,bf0, LG4, 0, af0, bf0, STAGE(0,0,1,kb+160), VM6); // p4
        PH(1, 1,1,0, af0, 1,bf1, LG8, 1, af1, bf0, STAGE(1,0,1,kb+160), NOP); // p5
        PH(1, 1,1,1, af1, 0,bf0, LG4, 0, af0, bf1, STAGE(0,1,0,kb+192), VM6); // p6
        PH(1, 0,0,0, af0, 1,bf0, LG8, 1, af1, bf1, STAGE(1,1,0,kb+192), NOP); // p7
    }
    {   // drain iteration (tiles NT-2, NT-1): only t+1.kh1 staging remains
        const int kb = (ITERS - 1) << 7;
        PH(1, 0,0,1, af1, 0,bf0, LG4, 0, af0, bf0, STAGE(0,1,1,kb+96), VM6);  // p0
        PH(1, 0,1,0, af0, 1,bf1, LG8, 1, af1, bf0, STAGE(1,1,1,kb+96), NOP);  // p1
        PH(1, 0,1,1, af1, 0,bf0, LG4, 0, af0, bf1, NOP,                VM4);  // p2
        PH(1, 1,0,0, af0, 1,bf0, LG8, 1, af1, bf1, NOP,                NOP);  // p3
        PH(1, 1,0,1, af1, 0,bf0, LG4, 0, af0, bf0, NOP,                VM0);  // p4
        PH(1, 1,1,0, af0, 1,bf1, LG8, 1, af1, bf0, NOP,                NOP);  // p5
        PH(1, 1,1,1, af1, 0,bf0, LG4, 0, af0, bf1, NOP,                NOP);  // p6
        PH(0, 0,0,0, af0, 0,bf0, LG0, 1, af1, bf1, NOP,                NOP);  // p7
    }

    // epilogue: C/D layout col = lane&15, row = (lane>>4)*4 + reg
#pragma unroll
    for (int m = 0; m < 8; ++m) {
        int row = brow + wm * 128 + m * 16 + kg * 4;
#pragma unroll
        for (int n = 0; n < 4; ++n) {
            int col = bcol + wn * 64 + n * 16 + fr;
            float bv = bias[col];
#pragma unroll
            for (int j = 0; j < 4; ++j)
                C[(size_t)(row + j) * N_DIM + col] = acc[m][n][j] + bv;
        }
    }
}

// ---- fallback (only if ws too small) ----
__global__ __launch_bounds__(256) void fallback_kernel(const float* __restrict__ x,
                                                       const int* __restrict__ w,
                                                       const float* __restrict__ wsc,
                                                       const float* __restrict__ bias,
                                                       float* __restrict__ out) {
    long idx = (long)blockIdx.x * 256 + threadIdx.x;
    int t = (int)(idx >> 12);
    int o = (int)(idx & 4095);
    float acc = 0.f;
    for (int j = 0; j < K_DIM / 2; ++j) {
        int b = w[o * (K_DIM / 2) + j];
        float s = wsc[(o << 8) + (j >> 3)];
        acc += x[(long)t * K_DIM + 2 * j]     * (FP4_LUT[(b >> 4) & 15] * s);
        acc += x[(long)t * K_DIM + 2 * j + 1] * (FP4_LUT[b & 15] * s);
    }
    out[idx] = acc + bias[o];
}

extern "C" void kernel_launch(void* const* d_in, const int* in_sizes, int n_in,
                              void* d_out, int out_size, void* d_ws, size_t ws_size,
                              hipStream_t stream) {
    const float* x    = (const float*)d_in[0];
    const int*   w    = (const int*)d_in[1];
    const float* wsc  = (const float*)d_in[2];
    const float* bias = (const float*)d_in[3];
    float* out = (float*)d_out;

    const size_t xh_bytes = (size_t)M_DIM * K_DIM * 2;   // 64 MB
    const size_t wh_bytes = (size_t)N_DIM * K_DIM * 2;   // 32 MB

    if (ws_size >= xh_bytes + wh_bytes) {
        _Float16* xh = (_Float16*)d_ws;
        _Float16* wh = (_Float16*)((char*)d_ws + xh_bytes);
        cvt_x_kernel<<<(M_DIM * K_DIM) / (256 * 8), 256, 0, stream>>>(x, xh);
        dequant_w_kernel<<<(N_DIM * (K_DIM / 2)) / (256 * 4), 256, 0, stream>>>(w, wsc, wh);
        gemm_f16_pf<<<(M_DIM / BM) * (N_DIM / BN), 512, 0, stream>>>(xh, wh, bias, out);
    } else {
        fallback_kernel<<<((long)M_DIM * N_DIM) / 256, 256, 0, stream>>>(x, w, wsc, bias, out);
    }
}